// Round 1
// baseline (434.656 us; speedup 1.0000x reference)
//
#include <hip/hip_runtime.h>
#include <hip/hip_bf16.h>

// CausalAttention: q=xWq,k=xWk,v=xWv; S=qk^T; causal mask (j>i -> -inf);
// softmax over AXIS=1 (query axis, i.e. COLUMN-wise over i) of S/32; out = W @ v.
// Strategy: P[i,j]=exp(s_ij/32) (no max-sub needed: |s/32|<~2.5), l_j=sum_{i>=j} P,
// fold 1/l_j into V rows -> out = P @ (V/l)^T via bt-GEMM. All GEMMs bf16 MFMA.

using bf16 = __hip_bfloat16;
typedef __attribute__((ext_vector_type(8))) short short8;
typedef __attribute__((ext_vector_type(4))) float f32x4;

// ---------------- fp32 -> bf16 convert (x4 per thread) ----------------
__global__ void cvt_kernel(const float* __restrict__ in, bf16* __restrict__ out) {
  size_t i = ((size_t)blockIdx.x * 256 + threadIdx.x) * 4;
  float4 v = *(const float4*)(in + i);
  alignas(8) bf16 h[4] = {__float2bfloat16(v.x), __float2bfloat16(v.y),
                          __float2bfloat16(v.z), __float2bfloat16(v.w)};
  *(unsigned long long*)(out + i) = *(const unsigned long long*)h;
}

// ---------------- W[k][n] fp32 -> Wt[n][k] bf16 (64x64 LDS transpose) ----------------
__global__ void wt_kernel(const float* __restrict__ W0, const float* __restrict__ W1,
                          const float* __restrict__ W2, bf16* __restrict__ Wt) {
  const float* W = blockIdx.z == 0 ? W0 : blockIdx.z == 1 ? W1 : W2;
  bf16* O = Wt + (size_t)blockIdx.z * 1048576ull;
  __shared__ float t[64][65];
  int n0 = blockIdx.x * 64, k0 = blockIdx.y * 64;
  int tid = threadIdx.x;
  for (int i = tid; i < 4096; i += 256) {
    int r = i >> 6, c = i & 63;
    t[r][c] = W[(size_t)(k0 + r) * 1024 + n0 + c];
  }
  __syncthreads();
  for (int i = tid; i < 4096; i += 256) {
    int r = i >> 6, c = i & 63;
    O[(size_t)(n0 + r) * 1024 + k0 + c] = __float2bfloat16(t[c][r]);
  }
}

__global__ void zero_kernel(float* p) { p[blockIdx.x * 256 + threadIdx.x] = 0.f; }

// ---------------- column sums of P (lower triangle), 128-row chunks + atomics ----------------
__global__ void colsum_kernel(const bf16* __restrict__ P, float* __restrict__ l) {
  int lb = blockIdx.z;
  const bf16* Pp = P + (size_t)lb * 4194304ull;
  int j = blockIdx.x * 256 + threadIdx.x;
  int jt = j >> 7;                      // column's 128-tile index
  if ((int)blockIdx.y < jt) return;     // chunk lies strictly above this column's tile (never written)
  int r0 = blockIdx.y * 128;
  float s = 0.f;
  for (int r = 0; r < 128; ++r) s += __bfloat162float(Pp[(size_t)(r0 + r) * 2048 + j]);
  atomicAdd(&l[lb * 2048 + j], s);      // diag-tile rows i<j hold explicit zeros -> safe
}

// ---------------- Vt[e][j] = bf16( V[j][e] / l_j )  (64x64 LDS transpose) ----------------
__global__ void vhat_kernel(const bf16* __restrict__ QKV, const float* __restrict__ l,
                            bf16* __restrict__ Vt) {
  int lb = blockIdx.z;
  const bf16* V = QKV + ((size_t)lb * 3 + 2) * 2097152ull;  // V slot of batch lb
  bf16* O = Vt + (size_t)lb * 2097152ull;
  const float* lc = l + lb * 2048;
  __shared__ float t[64][65];
  __shared__ float rl[64];
  int j0 = blockIdx.x * 64, e0 = blockIdx.y * 64;
  int tid = threadIdx.x;
  if (tid < 64) rl[tid] = 1.0f / lc[j0 + tid];
  for (int i = tid; i < 4096; i += 256) {
    int r = i >> 6, c = i & 63;
    t[r][c] = __bfloat162float(V[(size_t)(j0 + r) * 1024 + e0 + c]);
  }
  __syncthreads();
  for (int i = tid; i < 4096; i += 256) {
    int r = i >> 6, c = i & 63;  // out row e0+r, col j0+c
    O[(size_t)(e0 + r) * 2048 + j0 + c] = __float2bfloat16(t[c][r] * rl[c]);
  }
}

// ---------------- bt-GEMM: C[m,n] = sum_k A[m,k]*B[n,k], 128x128 tile, BK=64 ----------------
// EPI: 0 = bf16 store (QKV), 1 = P=exp(acc/32) causal-masked bf16 (S), 2 = fp32 store (PV out)
// VARK: K = (blockIdx.y+1)*128 (PV: stop at diagonal tile)
// z-indexing: A += (z/zdivA)*sA; B += (z%zmodB)*sB; C += z*sC
template <int EPI, bool VARK>
__global__ __launch_bounds__(256, 2) void gemm_bt(
    const bf16* __restrict__ A, const bf16* __restrict__ B, void* __restrict__ Cv,
    int lda, int ldb, int ldc, int Kin, int zdivA, int zmodB,
    unsigned long long sA, unsigned long long sB, unsigned long long sC) {
  if constexpr (EPI == 1) {
    if (blockIdx.x > blockIdx.y) return;  // strictly-upper score tile: skip
  }
  const int z = blockIdx.z;
  A += (unsigned long long)(z / zdivA) * sA;
  B += (unsigned long long)(z % zmodB) * sB;
  const int K = VARK ? (int)(blockIdx.y + 1) * 128 : Kin;

  alignas(16) __shared__ bf16 As[128 * 64];
  alignas(16) __shared__ bf16 Bs[128 * 64];

  const int tid = threadIdx.x, wave = tid >> 6, lane = tid & 63;
  const int m0 = blockIdx.y * 128, n0 = blockIdx.x * 128;
  const int srow = tid >> 3, scol = (tid & 7) * 8;   // staging: 16B per thread per chunk
  const int wm = (wave >> 1) * 64, wn = (wave & 1) * 64;
  const int fm = lane & 15, fk = (lane >> 4) * 8;    // MFMA A/B fragment coords

  f32x4 acc[4][4];
#pragma unroll
  for (int mi = 0; mi < 4; ++mi)
#pragma unroll
    for (int ni = 0; ni < 4; ++ni) acc[mi][ni] = (f32x4){0.f, 0.f, 0.f, 0.f};

  const bf16* Arow = A + (size_t)m0 * lda;
  const bf16* Brow = B + (size_t)n0 * ldb;

  for (int k0 = 0; k0 < K; k0 += 64) {
    __syncthreads();  // previous iteration's LDS reads done
#pragma unroll
    for (int c = 0; c < 4; ++c) {
      int row = c * 32 + srow;
      __builtin_amdgcn_global_load_lds(
          (const __attribute__((address_space(1))) void*)(Arow + (size_t)row * lda + k0 + scol),
          (__attribute__((address_space(3))) void*)(As + row * 64 + scol), 16, 0, 0);
    }
#pragma unroll
    for (int c = 0; c < 4; ++c) {
      int row = c * 32 + srow;
      __builtin_amdgcn_global_load_lds(
          (const __attribute__((address_space(1))) void*)(Brow + (size_t)row * ldb + k0 + scol),
          (__attribute__((address_space(3))) void*)(Bs + row * 64 + scol), 16, 0, 0);
    }
    __syncthreads();  // drains vmcnt -> staging visible
#pragma unroll
    for (int ks = 0; ks < 2; ++ks) {
      short8 af[4], bf_[4];
#pragma unroll
      for (int i = 0; i < 4; ++i) {
        af[i] = *(const short8*)(As + (wm + i * 16 + fm) * 64 + ks * 32 + fk);
        bf_[i] = *(const short8*)(Bs + (wn + i * 16 + fm) * 64 + ks * 32 + fk);
      }
#pragma unroll
      for (int mi = 0; mi < 4; ++mi)
#pragma unroll
        for (int ni = 0; ni < 4; ++ni)
          acc[mi][ni] = __builtin_amdgcn_mfma_f32_16x16x32_bf16(af[mi], bf_[ni], acc[mi][ni], 0, 0, 0);
    }
  }

  // epilogue — C/D layout: col = lane&15, row = (lane>>4)*4 + reg
  const int cr = (lane >> 4) * 4, cc = lane & 15;
  if constexpr (EPI == 2) {
    float* C = (float*)Cv + (unsigned long long)z * sC;
#pragma unroll
    for (int mi = 0; mi < 4; ++mi)
#pragma unroll
      for (int ni = 0; ni < 4; ++ni)
#pragma unroll
        for (int r = 0; r < 4; ++r)
          C[(size_t)(m0 + wm + mi * 16 + cr + r) * ldc + (n0 + wn + ni * 16 + cc)] = acc[mi][ni][r];
  } else {
    bf16* C = (bf16*)Cv + (unsigned long long)z * sC;
#pragma unroll
    for (int mi = 0; mi < 4; ++mi)
#pragma unroll
      for (int ni = 0; ni < 4; ++ni)
#pragma unroll
        for (int r = 0; r < 4; ++r) {
          int gm = m0 + wm + mi * 16 + cr + r;
          int gn = n0 + wn + ni * 16 + cc;
          if constexpr (EPI == 0) {
            C[(size_t)gm * ldc + gn] = __float2bfloat16(acc[mi][ni][r]);
          } else {
            float s = acc[mi][ni][r] * 0.03125f;  // 1/sqrt(1024)
            float p = (gn <= gm) ? __expf(s) : 0.f;  // causal: j<=i, else exact 0
            C[(size_t)gm * ldc + gn] = __float2bfloat16(p);
          }
        }
  }
}

// ---------------- host ----------------
extern "C" void kernel_launch(void* const* d_in, const int* in_sizes, int n_in,
                              void* d_out, int out_size, void* d_ws, size_t ws_size,
                              hipStream_t stream) {
  const float* x = (const float*)d_in[0];
  const float* Wq = (const float*)d_in[1];
  const float* Wk = (const float*)d_in[2];
  const float* Wv = (const float*)d_in[3];
  float* out = (float*)d_out;

  constexpr unsigned long long X_EL = 2048ull * 1024;     // per batch
  constexpr unsigned long long QKV_EL = 3ull * X_EL;
  constexpr unsigned long long P_EL = 2048ull * 2048;
  constexpr unsigned long long VT_EL = 1024ull * 2048;
  constexpr unsigned long long WT_B = 3ull * 1024 * 1024 * 2;
  constexpr unsigned long long PER_B = 2 * (X_EL + QKV_EL + P_EL + VT_EL) + 2048 * 4;

  size_t NB = 1;
  for (size_t nb : {(size_t)8, (size_t)4, (size_t)2})
    if (WT_B + nb * PER_B <= ws_size) { NB = nb; break; }

  char* p = (char*)d_ws;
  bf16* Wt = (bf16*)p;  p += WT_B;
  bf16* Xb = (bf16*)p;  p += 2 * NB * X_EL;
  bf16* QKV = (bf16*)p; p += 2 * NB * QKV_EL;
  bf16* P = (bf16*)p;   p += 2 * NB * P_EL;
  bf16* Vt = (bf16*)p;  p += 2 * NB * VT_EL;
  float* lbuf = (float*)p;

  wt_kernel<<<dim3(16, 16, 3), 256, 0, stream>>>(Wq, Wk, Wv, Wt);

  for (size_t b0 = 0; b0 < 8; b0 += NB) {
    // x chunk -> bf16
    cvt_kernel<<<dim3((unsigned)(NB * 2048)), 256, 0, stream>>>(x + b0 * X_EL, Xb);
    // Q,K,V = X @ W  (z = lb*3 + weight)
    gemm_bt<0, false><<<dim3(8, 16, (unsigned)(NB * 3)), 256, 0, stream>>>(
        Xb, Wt, QKV, 1024, 1024, 1024, 1024, 3, 3, X_EL, 1048576ull, X_EL);
    zero_kernel<<<dim3((unsigned)(NB * 8)), 256, 0, stream>>>(lbuf);
    // P = exp(QK^T/32) lower-triangle tiles, causal-masked
    gemm_bt<1, false><<<dim3(16, 16, (unsigned)NB), 256, 0, stream>>>(
        QKV, QKV + X_EL, P, 1024, 1024, 2048, 1024, 1, 1 << 30, QKV_EL, QKV_EL, P_EL);
    colsum_kernel<<<dim3(8, 16, (unsigned)NB), 256, 0, stream>>>(P, lbuf);
    vhat_kernel<<<dim3(32, 16, (unsigned)NB), 256, 0, stream>>>(QKV, lbuf, Vt);
    // out = P @ Vt^T, K stops at diagonal tile
    gemm_bt<2, true><<<dim3(8, 16, (unsigned)NB), 256, 0, stream>>>(
        P, Vt, out + b0 * X_EL, 2048, 2048, 1024, 0, 1, 1 << 30, P_EL, VT_EL, X_EL);
  }
}

// Round 2
// 395.819 us; speedup vs baseline: 1.0981x; 1.0981x over previous
//
#include <hip/hip_runtime.h>
#include <hip/hip_bf16.h>

// CausalAttention: q=xWq,k=xWk,v=xWv; S=qk^T; causal mask (j>i -> -inf);
// softmax over AXIS=1 (query axis, i.e. COLUMN-wise over i) of S/32; out = W @ v.
// Strategy: P[i,j]=exp(s_ij/32) (no max-sub needed: |s/32|<~2.5), l_j=sum_{i>=j} P
// (fused into P-GEMM epilogue), fold 1/l_j into V rows -> out = P @ (V/l)^T.
// All GEMMs bf16 MFMA, XOR-swizzled LDS (bank-conflict-free fragment reads).

using bf16 = __hip_bfloat16;
typedef __attribute__((ext_vector_type(8))) short short8;
typedef __attribute__((ext_vector_type(4))) float f32x4;

// ---------------- fp32 -> bf16 convert (x4 per thread) ----------------
__global__ void cvt_kernel(const float* __restrict__ in, bf16* __restrict__ out) {
  size_t i = ((size_t)blockIdx.x * 256 + threadIdx.x) * 4;
  float4 v = *(const float4*)(in + i);
  alignas(8) bf16 h[4] = {__float2bfloat16(v.x), __float2bfloat16(v.y),
                          __float2bfloat16(v.z), __float2bfloat16(v.w)};
  *(unsigned long long*)(out + i) = *(const unsigned long long*)h;
}

// ---------------- W[k][n] fp32 -> Wt[n][k] bf16 (64x64 LDS transpose) ----------------
__global__ void wt_kernel(const float* __restrict__ W0, const float* __restrict__ W1,
                          const float* __restrict__ W2, bf16* __restrict__ Wt) {
  const float* W = blockIdx.z == 0 ? W0 : blockIdx.z == 1 ? W1 : W2;
  bf16* O = Wt + (size_t)blockIdx.z * 1048576ull;
  __shared__ float t[64][65];
  int n0 = blockIdx.x * 64, k0 = blockIdx.y * 64;
  int tid = threadIdx.x;
  for (int i = tid; i < 4096; i += 256) {
    int r = i >> 6, c = i & 63;
    t[r][c] = W[(size_t)(k0 + r) * 1024 + n0 + c];
  }
  __syncthreads();
  for (int i = tid; i < 4096; i += 256) {
    int r = i >> 6, c = i & 63;
    O[(size_t)(n0 + r) * 1024 + k0 + c] = __float2bfloat16(t[c][r]);
  }
}

__global__ void zero_kernel(float* p) { p[blockIdx.x * 256 + threadIdx.x] = 0.f; }

// ---------------- Vt[e][j] = bf16( V[j][e] / l_j )  (64x64 LDS transpose) ----------------
__global__ void vhat_kernel(const bf16* __restrict__ QKV, const float* __restrict__ l,
                            bf16* __restrict__ Vt) {
  int lb = blockIdx.z;
  const bf16* V = QKV + ((size_t)lb * 3 + 2) * 2097152ull;  // V slot of batch lb
  bf16* O = Vt + (size_t)lb * 2097152ull;
  const float* lc = l + lb * 2048;
  __shared__ float t[64][65];
  __shared__ float rl[64];
  int j0 = blockIdx.x * 64, e0 = blockIdx.y * 64;
  int tid = threadIdx.x;
  if (tid < 64) rl[tid] = 1.0f / lc[j0 + tid];
  for (int i = tid; i < 4096; i += 256) {
    int r = i >> 6, c = i & 63;
    t[r][c] = __bfloat162float(V[(size_t)(j0 + r) * 1024 + e0 + c]);
  }
  __syncthreads();
  for (int i = tid; i < 4096; i += 256) {
    int r = i >> 6, c = i & 63;  // out row e0+r, col j0+c
    O[(size_t)(e0 + r) * 2048 + j0 + c] = __float2bfloat16(t[c][r] * rl[c]);
  }
}

// ---------------- bt-GEMM: C[m,n] = sum_k A[m,k]*B[n,k], 128x128 tile, BK=64 ----------------
// LDS layout XOR-swizzled: physical 16B-chunk = logical_chunk ^ (row&7). Staging keeps the
// wave-uniform-dest constraint (lane writes phys chunk lane&7) and instead permutes the
// GLOBAL source chunk; fragment reads then XOR with fm&7 -> 2-way max bank aliasing (free).
// EPI: 0 = bf16 store (QKV), 1 = P=exp(acc/32) causal-masked bf16 + fused column-sum -> lptr
// EPI: 2 = fp32 store (PV out). VARK: K = (blockIdx.y+1)*128 (PV: stop at diagonal tile).
// z-indexing: A += (z/zdivA)*sA; B += (z%zmodB)*sB; C += z*sC
template <int EPI, bool VARK>
__global__ __launch_bounds__(256, 4) void gemm_bt(
    const bf16* __restrict__ A, const bf16* __restrict__ B, void* __restrict__ Cv,
    int lda, int ldb, int ldc, int Kin, int zdivA, int zmodB,
    unsigned long long sA, unsigned long long sB, unsigned long long sC,
    float* __restrict__ lptr) {
  if constexpr (EPI == 1) {
    if (blockIdx.x > blockIdx.y) return;  // strictly-upper score tile: skip
  }
  const int z = blockIdx.z;
  A += (unsigned long long)(z / zdivA) * sA;
  B += (unsigned long long)(z % zmodB) * sB;
  const int K = VARK ? (int)(blockIdx.y + 1) * 128 : Kin;

  alignas(16) __shared__ bf16 As[128 * 64];
  alignas(16) __shared__ bf16 Bs[128 * 64];

  const int tid = threadIdx.x, wave = tid >> 6, lane = tid & 63;
  const int m0 = blockIdx.y * 128, n0 = blockIdx.x * 128;
  const int srow = tid >> 3;                                  // staging row (per 32-row group)
  const int scol_g = ((tid & 7) ^ (srow & 7)) * 8;            // swizzled GLOBAL chunk
  const int scol_l = (tid & 7) * 8;                           // physical LDS chunk
  const int wm = (wave >> 1) * 64, wn = (wave & 1) * 64;
  const int fm = lane & 15, sw = lane & 7, kg = lane >> 4;    // fragment coords

  f32x4 acc[4][4];
#pragma unroll
  for (int mi = 0; mi < 4; ++mi)
#pragma unroll
    for (int ni = 0; ni < 4; ++ni) acc[mi][ni] = (f32x4){0.f, 0.f, 0.f, 0.f};

  const bf16* Arow = A + (size_t)m0 * lda;
  const bf16* Brow = B + (size_t)n0 * ldb;

  for (int k0 = 0; k0 < K; k0 += 64) {
    __syncthreads();  // previous iteration's LDS reads done
#pragma unroll
    for (int c = 0; c < 4; ++c) {
      int row = c * 32 + srow;
      __builtin_amdgcn_global_load_lds(
          (const __attribute__((address_space(1))) void*)(Arow + (size_t)row * lda + k0 + scol_g),
          (__attribute__((address_space(3))) void*)(As + row * 64 + scol_l), 16, 0, 0);
    }
#pragma unroll
    for (int c = 0; c < 4; ++c) {
      int row = c * 32 + srow;
      __builtin_amdgcn_global_load_lds(
          (const __attribute__((address_space(1))) void*)(Brow + (size_t)row * ldb + k0 + scol_g),
          (__attribute__((address_space(3))) void*)(Bs + row * 64 + scol_l), 16, 0, 0);
    }
    __syncthreads();  // drains vmcnt -> staging visible
#pragma unroll
    for (int ks = 0; ks < 2; ++ks) {
      const int pc = ((ks * 4 + kg) ^ sw) * 8;  // swizzled chunk for this lane's rows
      short8 af[4], bf_[4];
#pragma unroll
      for (int i = 0; i < 4; ++i) {
        af[i] = *(const short8*)(As + (wm + i * 16 + fm) * 64 + pc);
        bf_[i] = *(const short8*)(Bs + (wn + i * 16 + fm) * 64 + pc);
      }
#pragma unroll
      for (int mi = 0; mi < 4; ++mi)
#pragma unroll
        for (int ni = 0; ni < 4; ++ni)
          acc[mi][ni] = __builtin_amdgcn_mfma_f32_16x16x32_bf16(af[mi], bf_[ni], acc[mi][ni], 0, 0, 0);
    }
  }

  // epilogue — C/D layout: col = lane&15, row = (lane>>4)*4 + reg
  const int cr = kg * 4, cc = fm;
  if constexpr (EPI == 2) {
    float* C = (float*)Cv + (unsigned long long)z * sC;
#pragma unroll
    for (int mi = 0; mi < 4; ++mi)
#pragma unroll
      for (int ni = 0; ni < 4; ++ni)
#pragma unroll
        for (int r = 0; r < 4; ++r)
          C[(size_t)(m0 + wm + mi * 16 + cr + r) * ldc + (n0 + wn + ni * 16 + cc)] = acc[mi][ni][r];
  } else if constexpr (EPI == 0) {
    bf16* C = (bf16*)Cv + (unsigned long long)z * sC;
#pragma unroll
    for (int mi = 0; mi < 4; ++mi)
#pragma unroll
      for (int ni = 0; ni < 4; ++ni)
#pragma unroll
        for (int r = 0; r < 4; ++r)
          C[(size_t)(m0 + wm + mi * 16 + cr + r) * ldc + (n0 + wn + ni * 16 + cc)] =
              __float2bfloat16(acc[mi][ni][r]);
  } else {
    // EPI == 1: P = exp(acc/32) causal-masked, plus fused column sums into lptr
    bf16* C = (bf16*)Cv + (unsigned long long)z * sC;
    float colpart[4] = {0.f, 0.f, 0.f, 0.f};
#pragma unroll
    for (int mi = 0; mi < 4; ++mi)
#pragma unroll
      for (int ni = 0; ni < 4; ++ni)
#pragma unroll
        for (int r = 0; r < 4; ++r) {
          int gm = m0 + wm + mi * 16 + cr + r;
          int gn = n0 + wn + ni * 16 + cc;
          float s = acc[mi][ni][r] * 0.03125f;      // 1/sqrt(1024)
          float p = (gn <= gm) ? __expf(s) : 0.f;   // causal: j<=i, else exact 0
          colpart[ni] += p;
          C[(size_t)gm * ldc + gn] = __float2bfloat16(p);
        }
    // reduce over the 4 row-groups of this wave (lane bits 4,5), then 1 atomic/column
    float* lcol = lptr + (size_t)z * 2048 + n0 + wn;
#pragma unroll
    for (int ni = 0; ni < 4; ++ni) {
      float s = colpart[ni];
      s += __shfl_xor(s, 16);
      s += __shfl_xor(s, 32);
      if (lane < 16) atomicAdd(&lcol[ni * 16 + lane], s);
    }
  }
}

// ---------------- host ----------------
extern "C" void kernel_launch(void* const* d_in, const int* in_sizes, int n_in,
                              void* d_out, int out_size, void* d_ws, size_t ws_size,
                              hipStream_t stream) {
  const float* x = (const float*)d_in[0];
  const float* Wq = (const float*)d_in[1];
  const float* Wk = (const float*)d_in[2];
  const float* Wv = (const float*)d_in[3];
  float* out = (float*)d_out;

  constexpr unsigned long long X_EL = 2048ull * 1024;     // per batch
  constexpr unsigned long long QKV_EL = 3ull * X_EL;
  constexpr unsigned long long P_EL = 2048ull * 2048;
  constexpr unsigned long long VT_EL = 1024ull * 2048;
  constexpr unsigned long long WT_B = 3ull * 1024 * 1024 * 2;
  constexpr unsigned long long PER_B = 2 * (X_EL + QKV_EL + P_EL + VT_EL) + 2048 * 4;

  size_t NB = 1;
  for (size_t nb : {(size_t)8, (size_t)4, (size_t)2})
    if (WT_B + nb * PER_B <= ws_size) { NB = nb; break; }

  char* p = (char*)d_ws;
  bf16* Wt = (bf16*)p;  p += WT_B;
  bf16* Xb = (bf16*)p;  p += 2 * NB * X_EL;
  bf16* QKV = (bf16*)p; p += 2 * NB * QKV_EL;
  bf16* P = (bf16*)p;   p += 2 * NB * P_EL;
  bf16* Vt = (bf16*)p;  p += 2 * NB * VT_EL;
  float* lbuf = (float*)p;

  wt_kernel<<<dim3(16, 16, 3), 256, 0, stream>>>(Wq, Wk, Wv, Wt);

  for (size_t b0 = 0; b0 < 8; b0 += NB) {
    // x chunk -> bf16
    cvt_kernel<<<dim3((unsigned)(NB * 2048)), 256, 0, stream>>>(x + b0 * X_EL, Xb);
    // Q,K,V = X @ W  (z = lb*3 + weight)
    gemm_bt<0, false><<<dim3(8, 16, (unsigned)(NB * 3)), 256, 0, stream>>>(
        Xb, Wt, QKV, 1024, 1024, 1024, 1024, 3, 3, X_EL, 1048576ull, X_EL, nullptr);
    zero_kernel<<<dim3((unsigned)(NB * 8)), 256, 0, stream>>>(lbuf);
    // P = exp(QK^T/32) lower-triangle tiles, causal-masked, fused column sums -> lbuf
    gemm_bt<1, false><<<dim3(16, 16, (unsigned)NB), 256, 0, stream>>>(
        QKV, QKV + X_EL, P, 1024, 1024, 2048, 1024, 1, 1 << 30, QKV_EL, QKV_EL, P_EL, lbuf);
    vhat_kernel<<<dim3(32, 16, (unsigned)NB), 256, 0, stream>>>(QKV, lbuf, Vt);
    // out = P @ Vt^T, K stops at diagonal tile
    gemm_bt<2, true><<<dim3(8, 16, (unsigned)NB), 256, 0, stream>>>(
        P, Vt, out + b0 * X_EL, 2048, 2048, 1024, 0, 1, 1 << 30, P_EL, VT_EL, X_EL, nullptr);
  }
}